// Round 23
// baseline (299.632 us; speedup 1.0000x reference)
//
#include <hip/hip_runtime.h>
#include <cmath>

#define SQ 4096
#define SK 4096
#define NH 16
#define DH 128
#define TQ 64
#define TK 64
#define TOPK 2048
#define NEG_SENTINEL (-3.0e38f)

typedef __attribute__((ext_vector_type(8))) short short8;
typedef __attribute__((ext_vector_type(4))) float f32x4;

#define QS_BYTES ((size_t)64 * 16 * 2 * 1024 * 16)   // [qtile][head][part][unit16B]

// Split f32 x into bf16 hi + bf16 lo (truncation split; residual exact).
__device__ __forceinline__ void cvt8(const float4 x0, const float4 x1,
                                     short8& hv, short8& lv) {
    const float xs[8] = {x0.x, x0.y, x0.z, x0.w, x1.x, x1.y, x1.z, x1.w};
    #pragma unroll
    for (int j = 0; j < 8; ++j) {
        const unsigned int b = __float_as_uint(xs[j]);
        const float hf = __uint_as_float(b & 0xFFFF0000u);
        const float r = xs[j] - hf;
        hv[j] = (short)(b >> 16);
        lv[j] = (short)(__float_as_uint(r) >> 16);
    }
}

__device__ __forceinline__ void gload_lds16(const void* g, void* l) {
    __builtin_amdgcn_global_load_lds(
        (const __attribute__((address_space(1))) unsigned int*)g,
        (__attribute__((address_space(3))) unsigned int*)l,
        16, 0, 0);
}

// ---------------------------------------------------------------------------
// Kernel 0: pre-split Q with w*scale folded in (r19, validated).
// ---------------------------------------------------------------------------
__global__ __launch_bounds__(256) void split_q_kernel(
    const float* __restrict__ qg,    // [SQ][NH][DH]
    const float* __restrict__ wg,    // [SQ][NH]
    short8* __restrict__ qs)         // [64][16][2][1024] 16B units
{
    __shared__ short8 LH[1024], LL[1024];   // 16KB + 16KB

    const int blk  = blockIdx.x;            // tile*16 + h
    const int tile = blk >> 4;
    const int h    = blk & 15;
    const int tid  = threadIdx.x;

    #pragma unroll
    for (int it = 0; it < 4; ++it) {
        const int gi = it * 256 + tid;      // r*16 + c (c fast)
        const int c  = gi & 15;
        const int r  = gi >> 4;
        const int row = tile * 64 + r;
        const float wv = wg[(size_t)row * NH + h] * 0.08838834764831845f;
        const size_t gb = (((size_t)row * NH + h) * DH) + c * 8;
        float4 x0 = *(const float4*)&qg[gb];
        float4 x1 = *(const float4*)&qg[gb + 4];
        x0.x *= wv; x0.y *= wv; x0.z *= wv; x0.w *= wv;
        x1.x *= wv; x1.y *= wv; x1.z *= wv; x1.w *= wv;
        short8 hv, lv;
        cvt8(x0, x1, hv, lv);
        const int u = c * 64 + (r ^ (c & 7));
        LH[u] = hv; LL[u] = lv;
    }
    __syncthreads();

    short8* dst = qs + (size_t)blk * 2048;
    #pragma unroll
    for (int it = 0; it < 4; ++it) {
        const int u = it * 256 + tid;
        dst[u]        = LH[u];
        dst[1024 + u] = LL[u];
    }
}

// ---------------------------------------------------------------------------
// Kernel 1: scores — half-buffer pipeline with WAVE REMAP at the CORRECT
// VGPR budget: wave = 16 q-rows x all 64 k-cols (each A-fragment read by
// exactly one wave -> A LDS-reads halve). B frags = 128 VGPR; total ~185,
// so __launch_bounds__(256, 2) (cap 256, NO spill — r21 spilled at cap 128).
// Occupancy 2 blocks/CU (8 waves), LDS traffic/tile -25%.
// ---------------------------------------------------------------------------
__global__ __launch_bounds__(256, 2) void scores_kernel(
    const short8* __restrict__ qs,   // pre-split (w-folded) Q
    const float* __restrict__ kg,    // [SK][DH]
    float* __restrict__ scores)      // [SQ][SK]
{
    const int bq = blockIdx.x;       // x = q-tile (XCD locality)
    const int bk = blockIdx.y;
    if (bk > bq) return;             // fully masked: no writes

    const int qbase = bq * TQ;
    const int kbase = bk * TK;
    const int tid = threadIdx.x;

    __shared__ short8 QsH[2][512], QsL[2][512];   // 32KB

    const int lane = tid & 63;
    const int wid  = tid >> 6;     // q-quarter (16 rows)
    const int l15  = lane & 15;
    const int l4   = lane >> 4;

    // ---- K fragments: all 64 k-cols per wave (128 VGPR) ----
    short8 bh[4][4], bl[4][4];
    #pragma unroll
    for (int ni = 0; ni < 4; ++ni)
        #pragma unroll
        for (int s = 0; s < 4; ++s) {
            const int key = kbase + ni * 16 + l15;
            const int c   = s * 4 + l4;
            const float4 x0 = *(const float4*)&kg[(size_t)key * DH + c * 8];
            const float4 x1 = *(const float4*)&kg[(size_t)key * DH + c * 8 + 4];
            cvt8(x0, x1, bh[ni][s], bl[ni][s]);
        }

    f32x4 sacc[4];
    #pragma unroll
    for (int ni = 0; ni < 4; ++ni) sacc[ni] = (f32x4){0.f, 0.f, 0.f, 0.f};

    const short8* qt = qs + (size_t)bq * 16 * 2048;

#define STAGE_HALF(HEAD, HF)                                               \
    {                                                                      \
        const short8* hb_ = qt + (size_t)(HEAD) * 2048;                    \
        _Pragma("unroll") for (int cc = 0; cc < 2; ++cc) {                 \
            const int c_ = (HF) * 8 + wid * 2 + cc;                        \
            const int d_ = (c_ & 7) * 64;                                  \
            gload_lds16(hb_ + c_ * 64 + lane,        &QsH[HF][d_]);        \
            gload_lds16(hb_ + 1024 + c_ * 64 + lane, &QsL[HF][d_]);        \
        }                                                                  \
    }

#define COMPUTE_HALF(HF)                                                   \
    {                                                                      \
        __builtin_amdgcn_s_setprio(1);                                     \
        _Pragma("unroll") for (int ss = 0; ss < 2; ++ss) {                 \
            const int s = (HF) * 2 + ss;                                   \
            const int c = s * 4 + l4;                                      \
            const int u = (c & 7) * 64 + ((wid * 16 + l15) ^ (c & 7));     \
            const short8 ah = QsH[HF][u];                                  \
            const short8 al = QsL[HF][u];                                  \
            _Pragma("unroll") for (int ni = 0; ni < 4; ++ni) {             \
                lac[ni] = __builtin_amdgcn_mfma_f32_16x16x32_bf16(ah, bh[ni][s], lac[ni], 0, 0, 0); \
                lac[ni] = __builtin_amdgcn_mfma_f32_16x16x32_bf16(ah, bl[ni][s], lac[ni], 0, 0, 0); \
                lac[ni] = __builtin_amdgcn_mfma_f32_16x16x32_bf16(al, bh[ni][s], lac[ni], 0, 0, 0); \
            }                                                              \
        }                                                                  \
        __builtin_amdgcn_s_setprio(0);                                     \
    }

    STAGE_HALF(0, 0)
    __syncthreads();

    for (int h = 0; h < NH; ++h) {
        f32x4 lac[4];
        #pragma unroll
        for (int ni = 0; ni < 4; ++ni) lac[ni] = (f32x4){0.f, 0.f, 0.f, 0.f};

        STAGE_HALF(h, 1)
        COMPUTE_HALF(0)
        __syncthreads();

        if (h + 1 < NH) STAGE_HALF(h + 1, 0)
        COMPUTE_HALF(1)

        // epilogue: sacc += relu(lac)   (w folded into Q)
        #pragma unroll
        for (int ni = 0; ni < 4; ++ni)
            #pragma unroll
            for (int j = 0; j < 4; ++j)
                sacc[ni][j] += fmaxf(lac[ni][j], 0.f);

        __syncthreads();
    }
#undef STAGE_HALF
#undef COMPUTE_HALF

    #pragma unroll
    for (int ni = 0; ni < 4; ++ni)
        #pragma unroll
        for (int j = 0; j < 4; ++j) {
            const int q  = qbase + wid * 16 + l4 * 4 + j;
            const int kk = kbase + ni * 16 + l15;
            scores[(size_t)q * SK + kk] = (kk <= q) ? sacc[ni][j] : NEG_SENTINEL;
        }
}

// ---------------------------------------------------------------------------
// Shared 2048-key bitonic sort: 256 thr x 8 keys, swizzle (t>>1)&7.
// Outer k loop stays RUNTIME (unrolling it explodes compile time — r20).
// ---------------------------------------------------------------------------
#define REG8(J)                                                            \
    {                                                                      \
        _Pragma("unroll")                                                  \
        for (int r = 0; r < 8; ++r) {                                      \
            if ((r & (J)) == 0) {                                          \
                const int i = (t << 3) | r;                                \
                const bool up = ((i & k) == 0);                            \
                const unsigned long long a = key[r], b = key[r | (J)];     \
                const unsigned long long mx = a > b ? a : b;               \
                const unsigned long long mn = a > b ? b : a;               \
                key[r]       = up ? mx : mn;                               \
                key[r | (J)] = up ? mn : mx;                               \
            }                                                              \
        }                                                                  \
    }

__device__ __forceinline__ void sort2048_emit(
    unsigned long long key[8], unsigned long long* cld,
    float* __restrict__ out_row, const int t)
{
    const int sw8 = (t >> 1) & 7;
    for (int k = 2; k <= 2048; k <<= 1) {
        for (int j = k >> 1; j >= 512; j >>= 1) {
            __syncthreads();
            #pragma unroll
            for (int r = 0; r < 8; ++r) cld[(t << 3) | (r ^ sw8)] = key[r];
            __syncthreads();
            #pragma unroll
            for (int r = 0; r < 8; ++r) {
                const int i = (t << 3) | r;
                const unsigned long long bb = cld[(((t << 3) | (r ^ sw8))) ^ j];
                const bool take_max = (((i & k) == 0) == ((i & j) == 0));
                const bool agtb = key[r] > bb;
                key[r] = (take_max == agtb) ? key[r] : bb;
            }
        }
        {
            const int j0 = (k >> 1) < 256 ? (k >> 1) : 256;
            for (int j = j0; j >= 8; j >>= 1) {
                #pragma unroll
                for (int r = 0; r < 8; ++r) {
                    const int i = (t << 3) | r;
                    const unsigned long long bb =
                        (unsigned long long)__shfl_xor((long long)key[r], j >> 3, 64);
                    const bool take_max = (((i & k) == 0) == ((i & j) == 0));
                    const bool agtb = key[r] > bb;
                    key[r] = (take_max == agtb) ? key[r] : bb;
                }
            }
        }
        if (k > 4) REG8(4)
        if (k > 2) REG8(2)
        REG8(1)
    }

    #pragma unroll
    for (int r2 = 0; r2 < 2; ++r2) {
        float4 o;
        o.x = (float)(4095u - (unsigned int)(key[r2 * 4 + 0] & 0xFFFFFFFFu));
        o.y = (float)(4095u - (unsigned int)(key[r2 * 4 + 1] & 0xFFFFFFFFu));
        o.z = (float)(4095u - (unsigned int)(key[r2 * 4 + 2] & 0xFFFFFFFFu));
        o.w = (float)(4095u - (unsigned int)(key[r2 * 4 + 3] & 0xFFFFFFFFu));
        *(float4*)&out_row[(t << 3) + r2 * 4] = o;
    }
}

// ---------------------------------------------------------------------------
// Kernel 2: FUSED topk (r22, unchanged).
// ---------------------------------------------------------------------------
#define REG4(J)                                                            \
    {                                                                      \
        _Pragma("unroll")                                                  \
        for (int r = 0; r < 4; ++r) {                                      \
            if ((r & (J)) == 0) {                                          \
                const int i = (t << 2) | r;                                \
                const bool up = ((i & k) == 0);                            \
                const unsigned long long a = key[r], b = key[r | (J)];     \
                const unsigned long long mx = a > b ? a : b;               \
                const unsigned long long mn = a > b ? b : a;               \
                key[r]       = up ? mx : mn;                               \
                key[r | (J)] = up ? mn : mx;                               \
            }                                                              \
        }                                                                  \
    }

__global__ __launch_bounds__(256) void topk_fused_kernel(
    const float* __restrict__ scores,
    float* __restrict__ out_idx)
{
    __shared__ unsigned long long cld[2048];
    __shared__ unsigned int wsum2[2][4];

    const int qrow = blockIdx.x;
    const int t    = threadIdx.x;
    const int lane = t & 63;
    const int wid  = t >> 6;

    if (qrow < 1024) {
        // ---- small path: 1024-wide network ----
        unsigned long long key[4];
        {
            const float4 v = *(const float4*)(scores + (size_t)qrow * SK + (t << 2));
            const float vs[4] = {v.x, v.y, v.z, v.w};
            #pragma unroll
            for (int rr = 0; rr < 4; ++rr) {
                const int i = (t << 2) | rr;
                const unsigned int b = __float_as_uint(vs[rr]);
                const unsigned int u = (b & 0x80000000u) ? ~b : (b | 0x80000000u);
                key[rr] = ((unsigned long long)u << 32) | (unsigned int)(4095 - i);
            }
        }

        const int sw4 = (t >> 2) & 3;
        for (int k = 2; k <= 1024; k <<= 1) {
            for (int j = k >> 1; j >= 256; j >>= 1) {
                __syncthreads();
                #pragma unroll
                for (int r = 0; r < 4; ++r) cld[(t << 2) | (r ^ sw4)] = key[r];
                __syncthreads();
                #pragma unroll
                for (int r = 0; r < 4; ++r) {
                    const int i = (t << 2) | r;
                    const unsigned long long bb = cld[(((t << 2) | (r ^ sw4))) ^ j];
                    const bool take_max = (((i & k) == 0) == ((i & j) == 0));
                    const bool agtb = key[r] > bb;
                    key[r] = (take_max == agtb) ? key[r] : bb;
                }
            }
            {
                const int j0 = (k >> 1) < 128 ? (k >> 1) : 128;
                for (int j = j0; j >= 4; j >>= 1) {
                    #pragma unroll
                    for (int r = 0; r < 4; ++r) {
                        const int i = (t << 2) | r;
                        const unsigned long long bb =
                            (unsigned long long)__shfl_xor((long long)key[r], j >> 2, 64);
                        const bool take_max = (((i & k) == 0) == ((i & j) == 0));
                        const bool agtb = key[r] > bb;
                        key[r] = (take_max == agtb) ? key[r] : bb;
                    }
                }
            }
            if (k > 2) REG4(2)
            REG4(1)
        }

        float* out_row = out_idx + (size_t)qrow * TOPK;
        {
            float4 o;
            o.x = (float)(4095u - (unsigned int)(key[0] & 0xFFFFFFFFu));
            o.y = (float)(4095u - (unsigned int)(key[1] & 0xFFFFFFFFu));
            o.z = (float)(4095u - (unsigned int)(key[2] & 0xFFFFFFFFu));
            o.w = (float)(4095u - (unsigned int)(key[3] & 0xFFFFFFFFu));
            *(float4*)&out_row[t << 2] = o;
        }
        {
            const int p = 1024 + (t << 2);    // iota tail (sentinel indices)
            float4 o;
            o.x = (float)(p + 0); o.y = (float)(p + 1);
            o.z = (float)(p + 2); o.w = (float)(p + 3);
            *(float4*)&out_row[p] = o;
        }
        return;
    }

    unsigned long long key[8];

    if (qrow < 2048) {
        // ---- prefix path ----
        const float* rowp = scores + (size_t)qrow * SK + (t << 3);
        #pragma unroll
        for (int r4 = 0; r4 < 2; ++r4) {
            const float4 v = *(const float4*)(rowp + r4 * 4);
            const float vs[4] = {v.x, v.y, v.z, v.w};
            #pragma unroll
            for (int rr = 0; rr < 4; ++rr) {
                const int r = r4 * 4 + rr;
                const int i = (t << 3) | r;
                const unsigned int b = __float_as_uint(vs[rr]);
                const unsigned int u = (b & 0x80000000u) ? ~b : (b | 0x80000000u);
                key[r] = ((unsigned long long)u << 32) | (unsigned int)(4095 - i);
            }
        }
    } else {
        // ---- select path: 16 values/thread over 4096 cols, clamped ----
        unsigned int u[16];
        {
            const int bc = t << 4;
            if (bc <= (qrow | 63)) {
                const float* rowp = scores + (size_t)qrow * SK + bc;
                #pragma unroll
                for (int r4 = 0; r4 < 4; ++r4) {
                    const float4 v = *(const float4*)(rowp + r4 * 4);
                    const float vs[4] = {v.x, v.y, v.z, v.w};
                    #pragma unroll
                    for (int rr = 0; rr < 4; ++rr) {
                        const int r = r4 * 4 + rr;
                        const unsigned int b = __float_as_uint(vs[rr]);
                        unsigned int uu = (b & 0x80000000u) ? ~b : (b | 0x80000000u);
                        if (bc + r > qrow) uu = 0u;
                        u[r] = uu;
                    }
                }
            } else {
                #pragma unroll
                for (int r = 0; r < 16; ++r) u[r] = 0u;
            }
        }

        // binary search, 1 barrier/iter via parity-buffered wsum
        unsigned int lo = 0x80000000u, hi = 0xFFFFFFFFu;
        unsigned int Tu = 0, count_gt = 0;
        int exact = 0;
        int pp = 0;
        while (lo < hi) {
            const unsigned int mid = lo + ((hi - lo) >> 1) + 1u;
            unsigned int c = 0;
            #pragma unroll
            for (int r = 0; r < 16; ++r) c += (u[r] >= mid) ? 1u : 0u;
            #pragma unroll
            for (int d = 32; d >= 1; d >>= 1) c += __shfl_xor(c, d, 64);
            if (lane == 0) wsum2[pp][wid] = c;
            __syncthreads();
            const unsigned int tot = wsum2[pp][0] + wsum2[pp][1] + wsum2[pp][2] + wsum2[pp][3];
            pp ^= 1;
            if (tot == 2048u) {
                Tu = mid - 1u;
                count_gt = 2048u;
                exact = 1;
                break;
            }
            if (tot > 2048u) lo = mid; else hi = mid - 1u;
        }
        if (!exact) {
            Tu = lo;
            unsigned int c = 0;
            #pragma unroll
            for (int r = 0; r < 16; ++r) c += (u[r] > Tu) ? 1u : 0u;
            #pragma unroll
            for (int d = 32; d >= 1; d >>= 1) c += __shfl_xor(c, d, 64);
            if (lane == 0) wsum2[pp][wid] = c;
            __syncthreads();
            count_gt = wsum2[pp][0] + wsum2[pp][1] + wsum2[pp][2] + wsum2[pp][3];
            pp ^= 1;
        }
        const unsigned int need = 2048u - count_gt;

        // stable exclusive prefixes (ascending index) of (gt, eq)
        unsigned int gtb[16], eqb[16];
        unsigned int cgt = 0, ceq = 0;
        #pragma unroll
        for (int r = 0; r < 16; ++r) {
            gtb[r] = cgt; eqb[r] = ceq;
            cgt += (u[r] > Tu) ? 1u : 0u;
            ceq += (u[r] == Tu) ? 1u : 0u;
        }
        unsigned int pack = (cgt << 16) | ceq;
        unsigned int inc = pack;
        #pragma unroll
        for (int d = 1; d < 64; d <<= 1) {
            const unsigned int v = __shfl_up(inc, d, 64);
            if (lane >= d) inc += v;
        }
        const unsigned int ex = inc - pack;
        if (lane == 63) wsum2[pp][wid] = inc;
        __syncthreads();
        unsigned int wex = 0;
        #pragma unroll
        for (int ww = 0; ww < 4; ++ww) wex += (ww < wid) ? wsum2[pp][ww] : 0u;
        const unsigned int gt0 = (wex >> 16) + (ex >> 16);
        const unsigned int eq0 = (wex & 0xFFFFu) + (ex & 0xFFFFu);

        // compact selected 2048 keys into cld
        #pragma unroll
        for (int r = 0; r < 16; ++r) {
            const unsigned int g = gt0 + gtb[r];
            const unsigned int e = eq0 + eqb[r];
            const int i = (t << 4) | r;
            const unsigned long long kk =
                ((unsigned long long)u[r] << 32) | (unsigned int)(4095 - i);
            if (u[r] > Tu) {
                cld[g + (e < need ? e : need)] = kk;
            } else if (u[r] == Tu && e < need) {
                cld[g + e] = kk;
            }
        }
        __syncthreads();

        #pragma unroll
        for (int r = 0; r < 8; ++r) key[r] = cld[(t << 3) | r];
        __syncthreads();
    }

    sort2048_emit(key, cld, out_idx + (size_t)qrow * TOPK, t);
}

extern "C" void kernel_launch(void* const* d_in, const int* in_sizes, int n_in,
                              void* d_out, int out_size, void* d_ws, size_t ws_size,
                              hipStream_t stream) {
    const float* q = (const float*)d_in[0];
    const float* k = (const float*)d_in[1];
    const float* w = (const float*)d_in[2];

    float* out        = (float*)d_out;
    float* out_topk   = out;
    float* out_scores = out + (size_t)SQ * TOPK;

    short8* qs = (ws_size >= QS_BYTES) ? (short8*)d_ws : (short8*)out_topk;

    split_q_kernel<<<SQ / 64 * NH, 256, 0, stream>>>(q, w, qs);

    scores_kernel<<<dim3(SQ / TQ, SK / TK), 256, 0, stream>>>(qs, k, out_scores);

    topk_fused_kernel<<<SQ, 256, 0, stream>>>(out_scores, out_topk);
}

// Round 24
// 252.579 us; speedup vs baseline: 1.1863x; 1.1863x over previous
//
#include <hip/hip_runtime.h>
#include <cmath>

#define SQ 4096
#define SK 4096
#define NH 16
#define DH 128
#define TQ 64
#define TK 64
#define TOPK 2048
#define NEG_SENTINEL (-3.0e38f)

typedef __attribute__((ext_vector_type(8))) short short8;
typedef __attribute__((ext_vector_type(4))) float f32x4;

#define QS_BYTES ((size_t)64 * 16 * 2 * 1024 * 16)   // [qtile][head][part][unit16B]

// Split f32 x into bf16 hi + bf16 lo (truncation split; residual exact).
__device__ __forceinline__ void cvt8(const float4 x0, const float4 x1,
                                     short8& hv, short8& lv) {
    const float xs[8] = {x0.x, x0.y, x0.z, x0.w, x1.x, x1.y, x1.z, x1.w};
    #pragma unroll
    for (int j = 0; j < 8; ++j) {
        const unsigned int b = __float_as_uint(xs[j]);
        const float hf = __uint_as_float(b & 0xFFFF0000u);
        const float r = xs[j] - hf;
        hv[j] = (short)(b >> 16);
        lv[j] = (short)(__float_as_uint(r) >> 16);
    }
}

__device__ __forceinline__ void gload_lds16(const void* g, void* l) {
    __builtin_amdgcn_global_load_lds(
        (const __attribute__((address_space(1))) unsigned int*)g,
        (__attribute__((address_space(3))) unsigned int*)l,
        16, 0, 0);
}

// ---------------------------------------------------------------------------
// Kernel 0: pre-split Q with w*scale folded in (w >= 0 => w*relu(x) =
// relu(w*x) exactly). LDS-transposed for coalesced writes. [r19 validated]
// ---------------------------------------------------------------------------
__global__ __launch_bounds__(256) void split_q_kernel(
    const float* __restrict__ qg,    // [SQ][NH][DH]
    const float* __restrict__ wg,    // [SQ][NH]
    short8* __restrict__ qs)         // [64][16][2][1024] 16B units
{
    __shared__ short8 LH[1024], LL[1024];   // 16KB + 16KB

    const int blk  = blockIdx.x;            // tile*16 + h
    const int tile = blk >> 4;
    const int h    = blk & 15;
    const int tid  = threadIdx.x;

    #pragma unroll
    for (int it = 0; it < 4; ++it) {
        const int gi = it * 256 + tid;      // r*16 + c (c fast)
        const int c  = gi & 15;
        const int r  = gi >> 4;
        const int row = tile * 64 + r;
        const float wv = wg[(size_t)row * NH + h] * 0.08838834764831845f;
        const size_t gb = (((size_t)row * NH + h) * DH) + c * 8;
        float4 x0 = *(const float4*)&qg[gb];
        float4 x1 = *(const float4*)&qg[gb + 4];
        x0.x *= wv; x0.y *= wv; x0.z *= wv; x0.w *= wv;
        x1.x *= wv; x1.y *= wv; x1.z *= wv; x1.w *= wv;
        short8 hv, lv;
        cvt8(x0, x1, hv, lv);
        const int u = c * 64 + (r ^ (c & 7));
        LH[u] = hv; LL[u] = lv;
    }
    __syncthreads();

    short8* dst = qs + (size_t)blk * 2048;
    #pragma unroll
    for (int it = 0; it < 4; ++it) {
        const int u = it * 256 + tid;
        dst[u]        = LH[u];
        dst[1024 + u] = LL[u];
    }
}

// ---------------------------------------------------------------------------
// Kernel 1: scores — r19 EXACT (best validated ~107us): half-buffer pipeline,
// 2x2 wave layout (A-read duplication is the price of 4 blocks/CU — both
// remap variants measured worse: spill at cap 128 (r21), reload+low-occ at
// cap 256 (r23)). w folded into Q; setprio around MFMA clusters.
// ---------------------------------------------------------------------------
__global__ __launch_bounds__(256, 4) void scores_kernel(
    const short8* __restrict__ qs,   // pre-split (w-folded) Q
    const float* __restrict__ kg,    // [SK][DH]
    float* __restrict__ scores)      // [SQ][SK]
{
    const int bq = blockIdx.x;       // x = q-tile (XCD locality)
    const int bk = blockIdx.y;
    if (bk > bq) return;             // fully masked: no writes

    const int qbase = bq * TQ;
    const int kbase = bk * TK;
    const int tid = threadIdx.x;

    __shared__ short8 QsH[2][512], QsL[2][512];   // 32KB

    const int lane = tid & 63;
    const int wid  = tid >> 6;
    const int wr   = wid >> 1;
    const int wc   = wid & 1;
    const int l15  = lane & 15;
    const int l4   = lane >> 4;

    short8 bh[2][4], bl[2][4];
    #pragma unroll
    for (int ni = 0; ni < 2; ++ni)
        #pragma unroll
        for (int s = 0; s < 4; ++s) {
            const int key = kbase + wc * 32 + ni * 16 + l15;
            const int c   = s * 4 + l4;
            const float4 x0 = *(const float4*)&kg[(size_t)key * DH + c * 8];
            const float4 x1 = *(const float4*)&kg[(size_t)key * DH + c * 8 + 4];
            cvt8(x0, x1, bh[ni][s], bl[ni][s]);
        }

    f32x4 sacc[2][2];
    #pragma unroll
    for (int mi = 0; mi < 2; ++mi)
        #pragma unroll
        for (int ni = 0; ni < 2; ++ni) sacc[mi][ni] = (f32x4){0.f, 0.f, 0.f, 0.f};

    const short8* qt = qs + (size_t)bq * 16 * 2048;

#define STAGE_HALF(HEAD, HF)                                               \
    {                                                                      \
        const short8* hb_ = qt + (size_t)(HEAD) * 2048;                    \
        _Pragma("unroll") for (int cc = 0; cc < 2; ++cc) {                 \
            const int c_ = (HF) * 8 + wid * 2 + cc;                        \
            const int d_ = (c_ & 7) * 64;                                  \
            gload_lds16(hb_ + c_ * 64 + lane,        &QsH[HF][d_]);        \
            gload_lds16(hb_ + 1024 + c_ * 64 + lane, &QsL[HF][d_]);        \
        }                                                                  \
    }

#define COMPUTE_HALF(HF)                                                   \
    {                                                                      \
        __builtin_amdgcn_s_setprio(1);                                     \
        _Pragma("unroll") for (int ss = 0; ss < 2; ++ss) {                 \
            const int s = (HF) * 2 + ss;                                   \
            short8 ah[2], al[2];                                           \
            _Pragma("unroll") for (int mi = 0; mi < 2; ++mi) {             \
                const int row = wr * 32 + mi * 16 + l15;                   \
                const int c   = s * 4 + l4;                                \
                const int u   = (c & 7) * 64 + (row ^ (c & 7));            \
                ah[mi] = QsH[HF][u];                                       \
                al[mi] = QsL[HF][u];                                       \
            }                                                              \
            _Pragma("unroll") for (int mi = 0; mi < 2; ++mi)               \
                _Pragma("unroll") for (int ni = 0; ni < 2; ++ni) {         \
                    lac[mi][ni] = __builtin_amdgcn_mfma_f32_16x16x32_bf16(ah[mi], bh[ni][s], lac[mi][ni], 0, 0, 0); \
                    lac[mi][ni] = __builtin_amdgcn_mfma_f32_16x16x32_bf16(ah[mi], bl[ni][s], lac[mi][ni], 0, 0, 0); \
                    lac[mi][ni] = __builtin_amdgcn_mfma_f32_16x16x32_bf16(al[mi], bh[ni][s], lac[mi][ni], 0, 0, 0); \
                }                                                          \
        }                                                                  \
        __builtin_amdgcn_s_setprio(0);                                     \
    }

    STAGE_HALF(0, 0)
    __syncthreads();

    for (int h = 0; h < NH; ++h) {
        f32x4 lac[2][2];
        #pragma unroll
        for (int mi = 0; mi < 2; ++mi)
            #pragma unroll
            for (int ni = 0; ni < 2; ++ni) lac[mi][ni] = (f32x4){0.f, 0.f, 0.f, 0.f};

        STAGE_HALF(h, 1)
        COMPUTE_HALF(0)
        __syncthreads();

        if (h + 1 < NH) STAGE_HALF(h + 1, 0)
        COMPUTE_HALF(1)

        // epilogue: sacc += relu(lac)   (w folded into Q)
        #pragma unroll
        for (int mi = 0; mi < 2; ++mi)
            #pragma unroll
            for (int ni = 0; ni < 2; ++ni)
                #pragma unroll
                for (int j = 0; j < 4; ++j)
                    sacc[mi][ni][j] += fmaxf(lac[mi][ni][j], 0.f);

        __syncthreads();
    }
#undef STAGE_HALF
#undef COMPUTE_HALF

    #pragma unroll
    for (int mi = 0; mi < 2; ++mi)
        #pragma unroll
        for (int ni = 0; ni < 2; ++ni)
            #pragma unroll
            for (int j = 0; j < 4; ++j) {
                const int q  = qbase + wr * 32 + mi * 16 + l4 * 4 + j;
                const int kk = kbase + wc * 32 + ni * 16 + l15;
                scores[(size_t)q * SK + kk] = (kk <= q) ? sacc[mi][ni][j] : NEG_SENTINEL;
            }
}

// ---------------------------------------------------------------------------
// Shared 2048-key bitonic sort: 256 thr x 8 keys, swizzle (t>>1)&7.
// Outer k loop stays RUNTIME (unrolling it explodes compile time — r20).
// ---------------------------------------------------------------------------
#define REG8(J)                                                            \
    {                                                                      \
        _Pragma("unroll")                                                  \
        for (int r = 0; r < 8; ++r) {                                      \
            if ((r & (J)) == 0) {                                          \
                const int i = (t << 3) | r;                                \
                const bool up = ((i & k) == 0);                            \
                const unsigned long long a = key[r], b = key[r | (J)];     \
                const unsigned long long mx = a > b ? a : b;               \
                const unsigned long long mn = a > b ? b : a;               \
                key[r]       = up ? mx : mn;                               \
                key[r | (J)] = up ? mn : mx;                               \
            }                                                              \
        }                                                                  \
    }

__device__ __forceinline__ void sort2048_emit(
    unsigned long long key[8], unsigned long long* cld,
    float* __restrict__ out_row, const int t)
{
    const int sw8 = (t >> 1) & 7;
    for (int k = 2; k <= 2048; k <<= 1) {
        for (int j = k >> 1; j >= 512; j >>= 1) {
            __syncthreads();
            #pragma unroll
            for (int r = 0; r < 8; ++r) cld[(t << 3) | (r ^ sw8)] = key[r];
            __syncthreads();
            #pragma unroll
            for (int r = 0; r < 8; ++r) {
                const int i = (t << 3) | r;
                const unsigned long long bb = cld[(((t << 3) | (r ^ sw8))) ^ j];
                const bool take_max = (((i & k) == 0) == ((i & j) == 0));
                const bool agtb = key[r] > bb;
                key[r] = (take_max == agtb) ? key[r] : bb;
            }
        }
        {
            const int j0 = (k >> 1) < 256 ? (k >> 1) : 256;
            for (int j = j0; j >= 8; j >>= 1) {
                #pragma unroll
                for (int r = 0; r < 8; ++r) {
                    const int i = (t << 3) | r;
                    const unsigned long long bb =
                        (unsigned long long)__shfl_xor((long long)key[r], j >> 3, 64);
                    const bool take_max = (((i & k) == 0) == ((i & j) == 0));
                    const bool agtb = key[r] > bb;
                    key[r] = (take_max == agtb) ? key[r] : bb;
                }
            }
        }
        if (k > 4) REG8(4)
        if (k > 2) REG8(2)
        REG8(1)
    }

    #pragma unroll
    for (int r2 = 0; r2 < 2; ++r2) {
        float4 o;
        o.x = (float)(4095u - (unsigned int)(key[r2 * 4 + 0] & 0xFFFFFFFFu));
        o.y = (float)(4095u - (unsigned int)(key[r2 * 4 + 1] & 0xFFFFFFFFu));
        o.z = (float)(4095u - (unsigned int)(key[r2 * 4 + 2] & 0xFFFFFFFFu));
        o.w = (float)(4095u - (unsigned int)(key[r2 * 4 + 3] & 0xFFFFFFFFu));
        *(float4*)&out_row[(t << 3) + r2 * 4] = o;
    }
}

// ---------------------------------------------------------------------------
// Kernel 2: FUSED topk over all 4096 rows [r19 validated]:
//   row <  1024: sort first 1024 (256x4), emit sorted 1024 + iota tail.
//   row <  2048: sorted first-2048 prefix (256x8).
//   row >= 2048: binary-search select (exact-count early exit) + stable
//                compaction (value desc, index asc) + shared 2048-sort.
// ---------------------------------------------------------------------------
#define REG4(J)                                                            \
    {                                                                      \
        _Pragma("unroll")                                                  \
        for (int r = 0; r < 4; ++r) {                                      \
            if ((r & (J)) == 0) {                                          \
                const int i = (t << 2) | r;                                \
                const bool up = ((i & k) == 0);                            \
                const unsigned long long a = key[r], b = key[r | (J)];     \
                const unsigned long long mx = a > b ? a : b;               \
                const unsigned long long mn = a > b ? b : a;               \
                key[r]       = up ? mx : mn;                               \
                key[r | (J)] = up ? mn : mx;                               \
            }                                                              \
        }                                                                  \
    }

__global__ __launch_bounds__(256) void topk_fused_kernel(
    const float* __restrict__ scores,
    float* __restrict__ out_idx)
{
    __shared__ unsigned long long cld[2048];
    __shared__ unsigned int wsum[4];

    const int qrow = blockIdx.x;
    const int t    = threadIdx.x;
    const int lane = t & 63;
    const int wid  = t >> 6;

    if (qrow < 1024) {
        // ---- small path: 1024-wide network ----
        unsigned long long key[4];
        {
            const float4 v = *(const float4*)(scores + (size_t)qrow * SK + (t << 2));
            const float vs[4] = {v.x, v.y, v.z, v.w};
            #pragma unroll
            for (int rr = 0; rr < 4; ++rr) {
                const int i = (t << 2) | rr;
                const unsigned int b = __float_as_uint(vs[rr]);
                const unsigned int u = (b & 0x80000000u) ? ~b : (b | 0x80000000u);
                key[rr] = ((unsigned long long)u << 32) | (unsigned int)(4095 - i);
            }
        }

        const int sw4 = (t >> 2) & 3;
        for (int k = 2; k <= 1024; k <<= 1) {
            for (int j = k >> 1; j >= 256; j >>= 1) {
                __syncthreads();
                #pragma unroll
                for (int r = 0; r < 4; ++r) cld[(t << 2) | (r ^ sw4)] = key[r];
                __syncthreads();
                #pragma unroll
                for (int r = 0; r < 4; ++r) {
                    const int i = (t << 2) | r;
                    const unsigned long long bb = cld[(((t << 2) | (r ^ sw4))) ^ j];
                    const bool take_max = (((i & k) == 0) == ((i & j) == 0));
                    const bool agtb = key[r] > bb;
                    key[r] = (take_max == agtb) ? key[r] : bb;
                }
            }
            {
                const int j0 = (k >> 1) < 128 ? (k >> 1) : 128;
                for (int j = j0; j >= 4; j >>= 1) {
                    #pragma unroll
                    for (int r = 0; r < 4; ++r) {
                        const int i = (t << 2) | r;
                        const unsigned long long bb =
                            (unsigned long long)__shfl_xor((long long)key[r], j >> 2, 64);
                        const bool take_max = (((i & k) == 0) == ((i & j) == 0));
                        const bool agtb = key[r] > bb;
                        key[r] = (take_max == agtb) ? key[r] : bb;
                    }
                }
            }
            if (k > 2) REG4(2)
            REG4(1)
        }

        float* out_row = out_idx + (size_t)qrow * TOPK;
        {
            float4 o;
            o.x = (float)(4095u - (unsigned int)(key[0] & 0xFFFFFFFFu));
            o.y = (float)(4095u - (unsigned int)(key[1] & 0xFFFFFFFFu));
            o.z = (float)(4095u - (unsigned int)(key[2] & 0xFFFFFFFFu));
            o.w = (float)(4095u - (unsigned int)(key[3] & 0xFFFFFFFFu));
            *(float4*)&out_row[t << 2] = o;
        }
        {
            const int p = 1024 + (t << 2);    // iota tail (sentinel indices)
            float4 o;
            o.x = (float)(p + 0); o.y = (float)(p + 1);
            o.z = (float)(p + 2); o.w = (float)(p + 3);
            *(float4*)&out_row[p] = o;
        }
        return;
    }

    unsigned long long key[8];

    if (qrow < 2048) {
        // ---- prefix path ----
        const float* rowp = scores + (size_t)qrow * SK + (t << 3);
        #pragma unroll
        for (int r4 = 0; r4 < 2; ++r4) {
            const float4 v = *(const float4*)(rowp + r4 * 4);
            const float vs[4] = {v.x, v.y, v.z, v.w};
            #pragma unroll
            for (int rr = 0; rr < 4; ++rr) {
                const int r = r4 * 4 + rr;
                const int i = (t << 3) | r;
                const unsigned int b = __float_as_uint(vs[rr]);
                const unsigned int u = (b & 0x80000000u) ? ~b : (b | 0x80000000u);
                key[r] = ((unsigned long long)u << 32) | (unsigned int)(4095 - i);
            }
        }
    } else {
        // ---- select path: 16 values/thread over 4096 cols, clamped ----
        unsigned int u[16];
        {
            const int bc = t << 4;
            if (bc <= (qrow | 63)) {
                const float* rowp = scores + (size_t)qrow * SK + bc;
                #pragma unroll
                for (int r4 = 0; r4 < 4; ++r4) {
                    const float4 v = *(const float4*)(rowp + r4 * 4);
                    const float vs[4] = {v.x, v.y, v.z, v.w};
                    #pragma unroll
                    for (int rr = 0; rr < 4; ++rr) {
                        const int r = r4 * 4 + rr;
                        const unsigned int b = __float_as_uint(vs[rr]);
                        unsigned int uu = (b & 0x80000000u) ? ~b : (b | 0x80000000u);
                        if (bc + r > qrow) uu = 0u;
                        u[r] = uu;
                    }
                }
            } else {
                #pragma unroll
                for (int r = 0; r < 16; ++r) u[r] = 0u;
            }
        }

        // binary search with exact-count early exit
        unsigned int lo = 0x80000000u, hi = 0xFFFFFFFFu;
        unsigned int Tu = 0, count_gt = 0;
        int exact = 0;
        while (lo < hi) {
            const unsigned int mid = lo + ((hi - lo) >> 1) + 1u;
            unsigned int c = 0;
            #pragma unroll
            for (int r = 0; r < 16; ++r) c += (u[r] >= mid) ? 1u : 0u;
            #pragma unroll
            for (int d = 32; d >= 1; d >>= 1) c += __shfl_xor(c, d, 64);
            if (lane == 0) wsum[wid] = c;
            __syncthreads();
            const unsigned int tot = wsum[0] + wsum[1] + wsum[2] + wsum[3];
            __syncthreads();
            if (tot == 2048u) {
                Tu = mid - 1u;
                count_gt = 2048u;
                exact = 1;
                break;
            }
            if (tot > 2048u) lo = mid; else hi = mid - 1u;
        }
        if (!exact) {
            Tu = lo;
            unsigned int c = 0;
            #pragma unroll
            for (int r = 0; r < 16; ++r) c += (u[r] > Tu) ? 1u : 0u;
            #pragma unroll
            for (int d = 32; d >= 1; d >>= 1) c += __shfl_xor(c, d, 64);
            if (lane == 0) wsum[wid] = c;
            __syncthreads();
            count_gt = wsum[0] + wsum[1] + wsum[2] + wsum[3];
            __syncthreads();
        }
        const unsigned int need = 2048u - count_gt;

        // stable exclusive prefixes (ascending index) of (gt, eq)
        unsigned int gtb[16], eqb[16];
        unsigned int cgt = 0, ceq = 0;
        #pragma unroll
        for (int r = 0; r < 16; ++r) {
            gtb[r] = cgt; eqb[r] = ceq;
            cgt += (u[r] > Tu) ? 1u : 0u;
            ceq += (u[r] == Tu) ? 1u : 0u;
        }
        unsigned int pack = (cgt << 16) | ceq;
        unsigned int inc = pack;
        #pragma unroll
        for (int d = 1; d < 64; d <<= 1) {
            const unsigned int v = __shfl_up(inc, d, 64);
            if (lane >= d) inc += v;
        }
        const unsigned int ex = inc - pack;
        if (lane == 63) wsum[wid] = inc;
        __syncthreads();
        unsigned int wex = 0;
        #pragma unroll
        for (int ww = 0; ww < 4; ++ww) wex += (ww < wid) ? wsum[ww] : 0u;
        const unsigned int gt0 = (wex >> 16) + (ex >> 16);
        const unsigned int eq0 = (wex & 0xFFFFu) + (ex & 0xFFFFu);

        // compact selected 2048 keys into cld
        #pragma unroll
        for (int r = 0; r < 16; ++r) {
            const unsigned int g = gt0 + gtb[r];
            const unsigned int e = eq0 + eqb[r];
            const int i = (t << 4) | r;
            const unsigned long long kk =
                ((unsigned long long)u[r] << 32) | (unsigned int)(4095 - i);
            if (u[r] > Tu) {
                cld[g + (e < need ? e : need)] = kk;
            } else if (u[r] == Tu && e < need) {
                cld[g + e] = kk;
            }
        }
        __syncthreads();

        #pragma unroll
        for (int r = 0; r < 8; ++r) key[r] = cld[(t << 3) | r];
        __syncthreads();
    }

    sort2048_emit(key, cld, out_idx + (size_t)qrow * TOPK, t);
}

extern "C" void kernel_launch(void* const* d_in, const int* in_sizes, int n_in,
                              void* d_out, int out_size, void* d_ws, size_t ws_size,
                              hipStream_t stream) {
    const float* q = (const float*)d_in[0];
    const float* k = (const float*)d_in[1];
    const float* w = (const float*)d_in[2];

    float* out        = (float*)d_out;
    float* out_topk   = out;
    float* out_scores = out + (size_t)SQ * TOPK;

    short8* qs = (ws_size >= QS_BYTES) ? (short8*)d_ws : (short8*)out_topk;

    split_q_kernel<<<SQ / 64 * NH, 256, 0, stream>>>(q, w, qs);

    scores_kernel<<<dim3(SQ / TQ, SK / TK), 256, 0, stream>>>(qs, k, out_scores);

    topk_fused_kernel<<<SQ, 256, 0, stream>>>(out_scores, out_topk);
}